// Round 11
// baseline (170.513 us; speedup 1.0000x reference)
//
#include <hip/hip_runtime.h>
#include <hip/hip_bf16.h>
#include <hip/hip_cooperative_groups.h>

namespace cg = cooperative_groups;

#define BATCH 8
#define SEQ   8192
#define DIM   512

typedef float f32x4 __attribute__((ext_vector_type(4)));
typedef unsigned short u16x4 __attribute__((ext_vector_type(4)));
typedef int i32x16 __attribute__((ext_vector_type(16)));

#define INV2PI   0.15915494309189535f
#define SQRT_DIM 22.62741699796952f
// -log2(10000)/256  (div[k] = 2^(C2*k) = exp(-2k*ln(10000)/512))
#define C2 (-0.05190512648261504f)

// Workspace: [0,256KB) seg ids (int32), [256KB, +8MB) pe table (bf16)
#define SEG_BYTES ((size_t)BATCH * SEQ * 4)
#define PE_BYTES  ((size_t)SEQ * DIM * 2)

// LDS index, +1 int per 8: 2-way bank alias only (free)
#define TIX(k) ((k) + ((k) >> 3))

// ===========================================================================
// Shared helpers
// ===========================================================================
__device__ __forceinline__ void pe_fill_row(unsigned short* __restrict__ pe,
                                            int pos, int lane) {
    const float posf = (float)pos;
    const int dA = lane << 2;
    const int dB = dA + 256;
    u16x4 vA, vB;
    #pragma unroll
    for (int j = 0; j < 2; ++j) {
        const float kA = (float)((dA >> 1) + j);
        float rA = posf * __builtin_amdgcn_exp2f(C2 * kA) * INV2PI;
        rA -= floorf(rA);
        vA[2 * j]     = __bfloat16_as_ushort(__float2bfloat16(__builtin_amdgcn_sinf(rA)));
        vA[2 * j + 1] = __bfloat16_as_ushort(__float2bfloat16(__builtin_amdgcn_cosf(rA)));

        const float kB = (float)((dB >> 1) + j);
        float rB = posf * __builtin_amdgcn_exp2f(C2 * kB) * INV2PI;
        rB -= floorf(rB);
        vB[2 * j]     = __bfloat16_as_ushort(__float2bfloat16(__builtin_amdgcn_sinf(rB)));
        vB[2 * j + 1] = __bfloat16_as_ushort(__float2bfloat16(__builtin_amdgcn_cosf(rB)));
    }
    unsigned short* prow = pe + (size_t)pos * DIM;
    *reinterpret_cast<u16x4*>(prow + dA) = vA;   // 8B/lane, dense 512B/wave
    *reinterpret_cast<u16x4*>(prow + dB) = vB;
}

__device__ __forceinline__ void out_row(const float* __restrict__ emb,
                                        const unsigned short* __restrict__ pe,
                                        float* __restrict__ out,
                                        int token, int sgv, int row, int lane) {
    const int dA = lane << 2;
    const int dB = dA + 256;
    const float* erow = emb + (size_t)token * DIM;
    const unsigned short* prow = pe + (size_t)sgv * DIM;

    const f32x4 eA = *reinterpret_cast<const f32x4*>(erow + dA);
    const f32x4 eB = *reinterpret_cast<const f32x4*>(erow + dB);
    const u16x4 bA = *reinterpret_cast<const u16x4*>(prow + dA);
    const u16x4 bB = *reinterpret_cast<const u16x4*>(prow + dB);

    float pA[4], pB[4];
    #pragma unroll
    for (int j = 0; j < 4; ++j) {
        pA[j] = __builtin_bit_cast(float, ((unsigned int)bA[j]) << 16);
        pB[j] = __builtin_bit_cast(float, ((unsigned int)bB[j]) << 16);
    }

    f32x4 oA, oB;
    oA.x = eA.x * SQRT_DIM + pA[0];  oA.y = eA.y * SQRT_DIM + pA[1];
    oA.z = eA.z * SQRT_DIM + pA[2];  oA.w = eA.w * SQRT_DIM + pA[3];
    oB.x = eB.x * SQRT_DIM + pB[0];  oB.y = eB.y * SQRT_DIM + pB[1];
    oB.z = eB.z * SQRT_DIM + pB[2];  oB.w = eB.w * SQRT_DIM + pB[3];

    float* orow = out + (size_t)row * DIM;
    __builtin_nontemporal_store(oA, reinterpret_cast<f32x4*>(orow + dA));
    __builtin_nontemporal_store(oB, reinterpret_cast<f32x4*>(orow + dB));
}

// ===========================================================================
// FUSED cooperative kernel: 1024 blocks x 256 threads (4 blocks/CU exactly).
//   Phase A: blocks 0-7 seg scan (in-place LDS, 36.9KB); blocks 8-1023 pe.
//   grid.sync()
//   Phase B: all blocks, R8 memory pattern; wave = 16 consecutive rows with
//            tok/seg batched via s_load_dwordx16, full unroll.
// ===========================================================================
#define F_BLOCKS 1024
#define F_TPB    256
#define F_CHUNK  (SEQ / F_TPB)                    // 32 tokens/thread (seg)
#define F_ROWS_PER_BLOCK ((BATCH * SEQ) / F_BLOCKS)  // 64
#define F_ROWS_PER_WAVE  (F_ROWS_PER_BLOCK / 4)      // 16

__global__ __launch_bounds__(F_TPB, 4)
void fused_kernel(const int* __restrict__ tok, int* __restrict__ seg,
                  const float* __restrict__ emb,
                  unsigned short* __restrict__ pe,
                  float* __restrict__ out) {
    __shared__ int s_tok[SEQ + SEQ / 8];   // 36,864 B
    __shared__ int s_r[4], s_v[4], s_c[4];

    const int bid  = (int)blockIdx.x;
    const int tid  = (int)threadIdx.x;
    const int lane = tid & 63;
    const int wv   = tid >> 6;

    // ----------------------------- phase A ------------------------------
    if (bid < BATCH) {
        const int* t   = tok + (size_t)bid * SEQ;
        int*       sgo = seg + (size_t)bid * SEQ;

        #pragma unroll
        for (int m = 0; m < F_CHUNK; ++m) {
            const int k = m * F_TPB + tid;
            s_tok[TIX(k)] = t[k];
        }
        __syncthreads();

        const int start = tid * F_CHUNK;
        const int end   = start + F_CHUNK;
        const int lo    = (start < 1) ? 1 : start;

        // pass 1: per-thread nc transform (reset,val)
        int reset = 0, val = 0;
        for (int i = lo; i < end; ++i) {
            const int c = s_tok[TIX(i)];
            if (c >= 36 && c <= 41) { reset = 1; val = 2; }
            if (c < 12) val -= 1;
        }
        int ir = reset, iv = val;
        #pragma unroll
        for (int off = 1; off < 64; off <<= 1) {
            const int pv = __shfl_up(iv, off);
            const int pr = __shfl_up(ir, off);
            if (lane >= off && !ir) { iv += pv; ir = pr; }
        }
        int er = __shfl_up(ir, 1), ev = __shfl_up(iv, 1);
        if (lane == 0) { er = 0; ev = 0; }
        if (lane == 63) { s_r[wv] = ir; s_v[wv] = iv; }
        __syncthreads();
        int bv = 0;
        for (int w = 0; w < wv; ++w) {
            if (s_r[w]) bv = s_v[w]; else bv += s_v[w];
        }
        const int nc_entry = er ? ev : (bv + ev);

        // pass 2: per-thread flag count
        int nc = nc_entry, total = 0;
        for (int i = lo; i < end; ++i) {
            const int c = s_tok[TIX(i)];
            const int p = s_tok[TIX(i - 1)];
            if (c >= 36 && c <= 41) nc = 2;
            const bool is_note = (c < 12);
            const int f = is_note ? (int)((p >= 12) || (nc > 0)) : (int)(p < 12);
            if (is_note) nc -= 1;
            total += f;
        }
        int it = total;
        #pragma unroll
        for (int off = 1; off < 64; off <<= 1) {
            const int pv = __shfl_up(it, off);
            if (lane >= off) it += pv;
        }
        int et = __shfl_up(it, 1);
        if (lane == 0) et = 0;
        if (lane == 63) s_c[wv] = it;
        __syncthreads();
        int boff = 0;
        for (int w = 0; w < wv; ++w) boff += s_c[w];
        int run = boff + et;

        // pass 3: in-place — seg values overwrite token buffer; prev token
        // carried in a register (saved before the sync so neighbor's
        // overwrite can't race us).
        int p = s_tok[TIX(start == 0 ? 0 : start - 1)];
        __syncthreads();
        nc = nc_entry;
        if (start == 0) s_tok[TIX(0)] = 0;
        for (int i = lo; i < end; ++i) {
            const int c = s_tok[TIX(i)];
            if (c >= 36 && c <= 41) nc = 2;
            const bool is_note = (c < 12);
            const int f = is_note ? (int)((p >= 12) || (nc > 0)) : (int)(p < 12);
            if (is_note) nc -= 1;
            run += f;
            s_tok[TIX(i)] = run;
            p = c;
        }
        __syncthreads();
        #pragma unroll
        for (int m = 0; m < F_CHUNK; ++m) {
            const int k = m * F_TPB + tid;
            sgo[k] = s_tok[TIX(k)];
        }
    } else {
        // pe fill: 1016 blocks x 4 waves = 4064 wave-slots over 8192 rows
        for (int pos = (bid - BATCH) * 4 + wv; pos < SEQ;
             pos += (F_BLOCKS - BATCH) * 4)
            pe_fill_row(pe, pos, lane);
    }

    cg::this_grid().sync();

    // ----------------------------- phase B ------------------------------
    // XCD slab swizzle: 1024 = 8 XCDs x 128 blocks; each XCD owns one batch.
    const int vb   = ((bid & 7) << 7) | (bid >> 3);
    const int base = __builtin_amdgcn_readfirstlane(
                        vb * F_ROWS_PER_BLOCK + wv * F_ROWS_PER_WAVE);

    // batched uniform loads: 16 tokens + 16 segs (s_load_dwordx16 each)
    const i32x16 tk = *reinterpret_cast<const i32x16*>(tok + base);
    const i32x16 sg = *reinterpret_cast<const i32x16*>(seg + base);

    #pragma unroll
    for (int r = 0; r < F_ROWS_PER_WAVE; ++r) {
        out_row(emb, pe, out, tk[r], sg[r], base + r, lane);
    }
}

// ===========================================================================
// Fallback path (exact R8 structure, proven 39.3us) — used if the
// cooperative launch is rejected (e.g. capture incompatibility).
// ===========================================================================
#define TPB_PREP  1024
#define SEG_CHUNK (SEQ / TPB_PREP)          // 8
#define NWAVE     (TPB_PREP / 64)           // 16
#define PE_ROWS_PER_BLOCK NWAVE
#define PE_BLOCKS (SEQ / PE_ROWS_PER_BLOCK) // 512

__global__ __launch_bounds__(TPB_PREP)
void prep_kernel(const int* __restrict__ tok, int* __restrict__ seg,
                 unsigned short* __restrict__ pe) {
    const int tid  = threadIdx.x;
    const int lane = tid & 63;
    const int wv   = tid >> 6;

    if (blockIdx.x >= BATCH) {
        const int pos = ((int)blockIdx.x - BATCH) * PE_ROWS_PER_BLOCK + wv;
        pe_fill_row(pe, pos, lane);
        return;
    }

    __shared__ int s_tok[SEQ + SEQ / 8];
    __shared__ int s_seg[SEQ + SEQ / 8];
    __shared__ int s_pr[NWAVE], s_pv[NWAVE], s_cnt[NWAVE];

    const int b  = blockIdx.x;
    const int* t = tok + (size_t)b * SEQ;
    int*      sg = seg + (size_t)b * SEQ;

    #pragma unroll
    for (int m = 0; m < SEG_CHUNK; ++m) {
        const int k = m * TPB_PREP + tid;
        s_tok[TIX(k)] = t[k];
    }
    __syncthreads();

    const int start = tid * SEG_CHUNK;
    const int end   = start + SEG_CHUNK;
    const int lo    = (start < 1) ? 1 : start;

    int reset = 0, val = 0;
    #pragma unroll
    for (int i = lo; i < end; ++i) {
        const int c = s_tok[TIX(i)];
        if (c >= 36 && c <= 41) { reset = 1; val = 2; }
        if (c < 12) val -= 1;
    }
    int ir = reset, iv = val;
    #pragma unroll
    for (int off = 1; off < 64; off <<= 1) {
        const int pv = __shfl_up(iv, off);
        const int pr = __shfl_up(ir, off);
        if (lane >= off && !ir) { iv += pv; ir = pr; }
    }
    int er = __shfl_up(ir, 1), ev = __shfl_up(iv, 1);
    if (lane == 0) { er = 0; ev = 0; }
    if (lane == 63) { s_pr[wv] = ir; s_pv[wv] = iv; }
    __syncthreads();
    int bv = 0;
    for (int w = 0; w < wv; ++w) {
        if (s_pr[w]) bv = s_pv[w]; else bv += s_pv[w];
    }
    const int nc_entry = er ? ev : (bv + ev);

    int nc = nc_entry, total = 0;
    #pragma unroll
    for (int i = lo; i < end; ++i) {
        const int c = s_tok[TIX(i)];
        const int p = s_tok[TIX(i - 1)];
        if (c >= 36 && c <= 41) nc = 2;
        const bool is_note = (c < 12);
        const int f = is_note ? (int)((p >= 12) || (nc > 0)) : (int)(p < 12);
        if (is_note) nc -= 1;
        total += f;
    }
    int it = total;
    #pragma unroll
    for (int off = 1; off < 64; off <<= 1) {
        const int pv = __shfl_up(it, off);
        if (lane >= off) it += pv;
    }
    int et = __shfl_up(it, 1);
    if (lane == 0) et = 0;
    if (lane == 63) s_cnt[wv] = it;
    __syncthreads();
    int boff = 0;
    for (int w = 0; w < wv; ++w) boff += s_cnt[w];
    int run = boff + et;

    nc = nc_entry;
    if (start == 0) s_seg[TIX(0)] = 0;
    #pragma unroll
    for (int i = lo; i < end; ++i) {
        const int c = s_tok[TIX(i)];
        const int p = s_tok[TIX(i - 1)];
        if (c >= 36 && c <= 41) nc = 2;
        const bool is_note = (c < 12);
        const int f = is_note ? (int)((p >= 12) || (nc > 0)) : (int)(p < 12);
        if (is_note) nc -= 1;
        run += f;
        s_seg[TIX(i)] = run;
    }
    __syncthreads();
    #pragma unroll
    for (int m = 0; m < SEG_CHUNK; ++m) {
        const int k = m * TPB_PREP + tid;
        sg[k] = s_seg[TIX(k)];
    }
}

#define OUT_BLOCKS ((BATCH * SEQ) / 4)   // 16384

__global__ __launch_bounds__(256)
void out_kernel(const int*   __restrict__ tok,
                const int*   __restrict__ seg,
                const float* __restrict__ emb,
                const unsigned short* __restrict__ pe,
                float*       __restrict__ out) {
    const int bid = (int)blockIdx.x;
    const int vb  = ((bid & 7) << 11) | (bid >> 3);
    const int lane = (int)threadIdx.x & 63;
    const int row  = __builtin_amdgcn_readfirstlane(
                        vb * 4 + ((int)threadIdx.x >> 6));
    out_row(emb, pe, out, tok[row], seg[row], row, lane);
}

__global__ __launch_bounds__(256)
void out_kernel_trig(const int*   __restrict__ tok,
                     const int*   __restrict__ seg,
                     const float* __restrict__ emb,
                     float*       __restrict__ out) {
    const int bid = (int)blockIdx.x;
    const int vb  = ((bid & 7) << 11) | (bid >> 3);
    const int lane = (int)threadIdx.x & 63;
    const int row  = __builtin_amdgcn_readfirstlane(
                        vb * 4 + ((int)threadIdx.x >> 6));

    const int   token = tok[row];
    const float segf  = (float)seg[row];
    const int dA = lane << 2;
    const int dB = dA + 256;

    const float* erow = emb + (size_t)token * DIM;
    const f32x4 eA = *reinterpret_cast<const f32x4*>(erow + dA);
    const f32x4 eB = *reinterpret_cast<const f32x4*>(erow + dB);

    float vA[4], vB[4];
    #pragma unroll
    for (int j = 0; j < 2; ++j) {
        const float kA = (float)((dA >> 1) + j);
        float rA = segf * __builtin_amdgcn_exp2f(C2 * kA) * INV2PI;
        rA -= floorf(rA);
        vA[2 * j]     = __builtin_amdgcn_sinf(rA);
        vA[2 * j + 1] = __builtin_amdgcn_cosf(rA);
        const float kB = (float)((dB >> 1) + j);
        float rB = segf * __builtin_amdgcn_exp2f(C2 * kB) * INV2PI;
        rB -= floorf(rB);
        vB[2 * j]     = __builtin_amdgcn_sinf(rB);
        vB[2 * j + 1] = __builtin_amdgcn_cosf(rB);
    }

    f32x4 oA, oB;
    oA.x = eA.x * SQRT_DIM + vA[0];  oA.y = eA.y * SQRT_DIM + vA[1];
    oA.z = eA.z * SQRT_DIM + vA[2];  oA.w = eA.w * SQRT_DIM + vA[3];
    oB.x = eB.x * SQRT_DIM + vB[0];  oB.y = eB.y * SQRT_DIM + vB[1];
    oB.z = eB.z * SQRT_DIM + vB[2];  oB.w = eB.w * SQRT_DIM + vB[3];

    float* orow = out + (size_t)row * DIM;
    __builtin_nontemporal_store(oA, reinterpret_cast<f32x4*>(orow + dA));
    __builtin_nontemporal_store(oB, reinterpret_cast<f32x4*>(orow + dB));
}

extern "C" void kernel_launch(void* const* d_in, const int* in_sizes, int n_in,
                              void* d_out, int out_size, void* d_ws, size_t ws_size,
                              hipStream_t stream) {
    const int*   tok = (const int*)d_in[0];     // (BATCH, SEQ) int32
    const float* emb = (const float*)d_in[1];   // (VOCAB, DIM) f32
    float*       out = (float*)d_out;           // (BATCH, SEQ, DIM) f32
    int*            seg = (int*)d_ws;
    unsigned short* pe  = (unsigned short*)((char*)d_ws + SEG_BYTES);

    const bool have_pe_ws = (ws_size >= SEG_BYTES + PE_BYTES);

    if (have_pe_ws) {
        void* args[] = { (void*)&tok, (void*)&seg, (void*)&emb,
                         (void*)&pe,  (void*)&out };
        hipError_t err = hipLaunchCooperativeKernel(
            fused_kernel, dim3(F_BLOCKS), dim3(F_TPB), args, 0u, stream);
        if (err == hipSuccess) return;
        (void)hipGetLastError();   // clear sticky error, fall back to 2-kernel
        prep_kernel<<<BATCH + PE_BLOCKS, TPB_PREP, 0, stream>>>(tok, seg, pe);
        out_kernel<<<OUT_BLOCKS, 256, 0, stream>>>(tok, seg, emb, pe, out);
    } else {
        prep_kernel<<<BATCH, TPB_PREP, 0, stream>>>(tok, seg, pe);
        out_kernel_trig<<<OUT_BLOCKS, 256, 0, stream>>>(tok, seg, emb, out);
    }
}

// Round 12
// 62.122 us; speedup vs baseline: 2.7448x; 2.7448x over previous
//
#include <hip/hip_runtime.h>
#include <hip/hip_bf16.h>

#define BATCH 8
#define SEQ   8192
#define DIM   512

typedef float f32x4 __attribute__((ext_vector_type(4)));
typedef unsigned short u16x4 __attribute__((ext_vector_type(4)));

#define INV2PI   0.15915494309189535f
#define SQRT_DIM 22.62741699796952f
// -log2(10000)/256  (div[k] = 2^(C2*k) = exp(-2k*ln(10000)/512))
#define C2 (-0.05190512648261504f)

// Workspace: [0,256KB) seg ids (int32), [256KB, +8MB) pe table (bf16)
#define SEG_BYTES ((size_t)BATCH * SEQ * 4)
#define PE_BYTES  ((size_t)SEQ * DIM * 2)

#define TPB_PREP  1024
#define SEG_CHUNK (SEQ / TPB_PREP)          // 8 tokens / thread
#define NWAVE     (TPB_PREP / 64)           // 16
#define PE_ROWS_PER_BLOCK NWAVE             // 16 rows (1 wave = 1 row)
#define PE_BLOCKS (SEQ / PE_ROWS_PER_BLOCK) // 512

// LDS index, +1 int per 8: addr = 9t+j -> 2-way bank alias only (free)
#define TIX(k) ((k) + ((k) >> 3))

// ---------------------------------------------------------------------------
// prep_kernel (unchanged from R8 — proven)
//   blocks [0,8)     : segment-id scan, one block (1024 thr) per batch row
//   blocks [8,8+512) : bf16 pe fill, 16 rows/block, dA/dB dense lane layout
// ---------------------------------------------------------------------------
__global__ __launch_bounds__(TPB_PREP)
void prep_kernel(const int* __restrict__ tok, int* __restrict__ seg,
                 unsigned short* __restrict__ pe) {
    const int tid  = threadIdx.x;
    const int lane = tid & 63;
    const int wv   = tid >> 6;

    if (blockIdx.x >= BATCH) {
        // ------------------- bf16 pe table fill (dA/dB dense) ------------
        const int pos = ((int)blockIdx.x - BATCH) * PE_ROWS_PER_BLOCK + wv;
        const float posf = (float)pos;
        const int dA = lane << 2;        // elements [dA, dA+4)
        const int dB = dA + 256;         // elements [dB, dB+4)

        u16x4 vA, vB;
        #pragma unroll
        for (int j = 0; j < 2; ++j) {
            const float kA = (float)((dA >> 1) + j);
            const float divA = __builtin_amdgcn_exp2f(C2 * kA);
            float rA = posf * divA * INV2PI;  rA -= floorf(rA);
            vA[2 * j]     = __bfloat16_as_ushort(__float2bfloat16(__builtin_amdgcn_sinf(rA)));
            vA[2 * j + 1] = __bfloat16_as_ushort(__float2bfloat16(__builtin_amdgcn_cosf(rA)));

            const float kB = (float)((dB >> 1) + j);
            const float divB = __builtin_amdgcn_exp2f(C2 * kB);
            float rB = posf * divB * INV2PI;  rB -= floorf(rB);
            vB[2 * j]     = __bfloat16_as_ushort(__float2bfloat16(__builtin_amdgcn_sinf(rB)));
            vB[2 * j + 1] = __bfloat16_as_ushort(__float2bfloat16(__builtin_amdgcn_cosf(rB)));
        }
        unsigned short* prow = pe + (size_t)pos * DIM;
        *reinterpret_cast<u16x4*>(prow + dA) = vA;   // 8B/lane, 512B dense/wave
        *reinterpret_cast<u16x4*>(prow + dB) = vB;
        return;
    }

    // --------------------------- segment scan ----------------------------
    __shared__ int s_tok[SEQ + SEQ / 8];   // 36 KB
    __shared__ int s_seg[SEQ + SEQ / 8];   // 36 KB
    __shared__ int s_pr[NWAVE], s_pv[NWAVE], s_cnt[NWAVE];

    const int b  = blockIdx.x;
    const int* t = tok + (size_t)b * SEQ;
    int*      sg = seg + (size_t)b * SEQ;

    #pragma unroll
    for (int m = 0; m < SEG_CHUNK; ++m) {
        const int k = m * TPB_PREP + tid;
        s_tok[TIX(k)] = t[k];
    }
    __syncthreads();

    const int start = tid * SEG_CHUNK;
    const int end   = start + SEG_CHUNK;
    const int lo    = (start < 1) ? 1 : start;

    // ---- pass 1: per-thread nc transform --------------------------------
    int reset = 0, val = 0;
    #pragma unroll
    for (int i = lo; i < end; ++i) {
        const int c = s_tok[TIX(i)];
        if (c >= 36 && c <= 41) { reset = 1; val = 2; }
        if (c < 12) val -= 1;
    }

    int ir = reset, iv = val;
    #pragma unroll
    for (int off = 1; off < 64; off <<= 1) {
        const int pv = __shfl_up(iv, off);
        const int pr = __shfl_up(ir, off);
        if (lane >= off && !ir) { iv += pv; ir = pr; }
    }
    int er = __shfl_up(ir, 1), ev = __shfl_up(iv, 1);
    if (lane == 0) { er = 0; ev = 0; }
    if (lane == 63) { s_pr[wv] = ir; s_pv[wv] = iv; }
    __syncthreads();
    int bv = 0;
    for (int w = 0; w < wv; ++w) {
        if (s_pr[w]) bv = s_pv[w]; else bv += s_pv[w];
    }
    const int nc_entry = er ? ev : (bv + ev);

    // ---- pass 2: per-thread flag count ----------------------------------
    int nc = nc_entry, total = 0;
    #pragma unroll
    for (int i = lo; i < end; ++i) {
        const int c = s_tok[TIX(i)];
        const int p = s_tok[TIX(i - 1)];
        if (c >= 36 && c <= 41) nc = 2;
        const bool is_note = (c < 12);
        const int f = is_note ? (int)((p >= 12) || (nc > 0)) : (int)(p < 12);
        if (is_note) nc -= 1;
        total += f;
    }

    int it = total;
    #pragma unroll
    for (int off = 1; off < 64; off <<= 1) {
        const int pv = __shfl_up(it, off);
        if (lane >= off) it += pv;
    }
    int et = __shfl_up(it, 1);
    if (lane == 0) et = 0;
    if (lane == 63) s_cnt[wv] = it;
    __syncthreads();
    int boff = 0;
    for (int w = 0; w < wv; ++w) boff += s_cnt[w];
    int run = boff + et;

    // ---- pass 3: recompute flags, cumsum into LDS, flush coalesced ------
    nc = nc_entry;
    if (start == 0) s_seg[TIX(0)] = 0;
    #pragma unroll
    for (int i = lo; i < end; ++i) {
        const int c = s_tok[TIX(i)];
        const int p = s_tok[TIX(i - 1)];
        if (c >= 36 && c <= 41) nc = 2;
        const bool is_note = (c < 12);
        const int f = is_note ? (int)((p >= 12) || (nc > 0)) : (int)(p < 12);
        if (is_note) nc -= 1;
        run += f;
        s_seg[TIX(i)] = run;
    }
    __syncthreads();
    #pragma unroll
    for (int m = 0; m < SEG_CHUNK; ++m) {
        const int k = m * TPB_PREP + tid;
        sg[k] = s_seg[TIX(k)];
    }
}

// ---------------------------------------------------------------------------
// out_kernel: exact R8 (39.3us best). DIAGNOSTIC ROUND: launched TWICE —
// idempotent (rewrites identical bytes, inputs untouched), so the second
// launch's marginal time = out_kernel's true L2-warm duration.
// ---------------------------------------------------------------------------
#define OUT_BLOCKS ((BATCH * SEQ) / 4)   // 16384

__global__ __launch_bounds__(256)
void out_kernel(const int*   __restrict__ tok,
                const int*   __restrict__ seg,
                const float* __restrict__ emb,
                const unsigned short* __restrict__ pe,
                float*       __restrict__ out) {
    // bijective slab swizzle: 16384 = 8 * 2048; each XCD owns one batch
    const int bid = (int)blockIdx.x;
    const int vb  = ((bid & 7) << 11) | (bid >> 3);

    const int lane = (int)threadIdx.x & 63;
    const int row  = __builtin_amdgcn_readfirstlane(
                        vb * 4 + ((int)threadIdx.x >> 6));

    const int token = tok[row];   // scalar load (uniform)
    const int sgv   = seg[row];   // scalar load (uniform)

    const int dA = lane << 2;
    const int dB = dA + 256;

    const float* erow = emb + (size_t)token * DIM;
    const unsigned short* prow = pe + (size_t)sgv * DIM;

    const f32x4 eA = *reinterpret_cast<const f32x4*>(erow + dA);
    const f32x4 eB = *reinterpret_cast<const f32x4*>(erow + dB);
    const u16x4 bA = *reinterpret_cast<const u16x4*>(prow + dA);
    const u16x4 bB = *reinterpret_cast<const u16x4*>(prow + dB);

    float pA[4], pB[4];
    #pragma unroll
    for (int j = 0; j < 4; ++j) {
        pA[j] = __builtin_bit_cast(float, ((unsigned int)bA[j]) << 16);
        pB[j] = __builtin_bit_cast(float, ((unsigned int)bB[j]) << 16);
    }

    f32x4 oA, oB;
    oA.x = eA.x * SQRT_DIM + pA[0];  oA.y = eA.y * SQRT_DIM + pA[1];
    oA.z = eA.z * SQRT_DIM + pA[2];  oA.w = eA.w * SQRT_DIM + pA[3];
    oB.x = eB.x * SQRT_DIM + pB[0];  oB.y = eB.y * SQRT_DIM + pB[1];
    oB.z = eB.z * SQRT_DIM + pB[2];  oB.w = eB.w * SQRT_DIM + pB[3];

    float* orow = out + (size_t)row * DIM;
    __builtin_nontemporal_store(oA, reinterpret_cast<f32x4*>(orow + dA));
    __builtin_nontemporal_store(oB, reinterpret_cast<f32x4*>(orow + dB));
}

// ---------------------------------------------------------------------------
// Fallback out (ws too small for pe table): inline trig, R8 layout.
// ---------------------------------------------------------------------------
__global__ __launch_bounds__(256)
void out_kernel_trig(const int*   __restrict__ tok,
                     const int*   __restrict__ seg,
                     const float* __restrict__ emb,
                     float*       __restrict__ out) {
    const int bid = (int)blockIdx.x;
    const int vb  = ((bid & 7) << 11) | (bid >> 3);

    const int lane = (int)threadIdx.x & 63;
    const int row  = __builtin_amdgcn_readfirstlane(
                        vb * 4 + ((int)threadIdx.x >> 6));

    const int   token = tok[row];
    const float segf  = (float)seg[row];

    const int dA = lane << 2;
    const int dB = dA + 256;

    const float* erow = emb + (size_t)token * DIM;
    const f32x4 eA = *reinterpret_cast<const f32x4*>(erow + dA);
    const f32x4 eB = *reinterpret_cast<const f32x4*>(erow + dB);

    float vA[4], vB[4];
    #pragma unroll
    for (int j = 0; j < 2; ++j) {
        const float kA = (float)((dA >> 1) + j);
        float rA = segf * __builtin_amdgcn_exp2f(C2 * kA) * INV2PI;
        rA -= floorf(rA);
        vA[2 * j]     = __builtin_amdgcn_sinf(rA);
        vA[2 * j + 1] = __builtin_amdgcn_cosf(rA);

        const float kB = (float)((dB >> 1) + j);
        float rB = segf * __builtin_amdgcn_exp2f(C2 * kB) * INV2PI;
        rB -= floorf(rB);
        vB[2 * j]     = __builtin_amdgcn_sinf(rB);
        vB[2 * j + 1] = __builtin_amdgcn_cosf(rB);
    }

    f32x4 oA, oB;
    oA.x = eA.x * SQRT_DIM + vA[0];  oA.y = eA.y * SQRT_DIM + vA[1];
    oA.z = eA.z * SQRT_DIM + vA[2];  oA.w = eA.w * SQRT_DIM + vA[3];
    oB.x = eB.x * SQRT_DIM + vB[0];  oB.y = eB.y * SQRT_DIM + vB[1];
    oB.z = eB.z * SQRT_DIM + vB[2];  oB.w = eB.w * SQRT_DIM + vB[3];

    float* orow = out + (size_t)row * DIM;
    __builtin_nontemporal_store(oA, reinterpret_cast<f32x4*>(orow + dA));
    __builtin_nontemporal_store(oB, reinterpret_cast<f32x4*>(orow + dB));
}

extern "C" void kernel_launch(void* const* d_in, const int* in_sizes, int n_in,
                              void* d_out, int out_size, void* d_ws, size_t ws_size,
                              hipStream_t stream) {
    const int*   tok = (const int*)d_in[0];     // (BATCH, SEQ) int32
    const float* emb = (const float*)d_in[1];   // (VOCAB, DIM) f32
    float*       out = (float*)d_out;           // (BATCH, SEQ, DIM) f32
    int*            seg = (int*)d_ws;
    unsigned short* pe  = (unsigned short*)((char*)d_ws + SEG_BYTES);

    const bool have_pe_ws = (ws_size >= SEG_BYTES + PE_BYTES);

    if (have_pe_ws) {
        prep_kernel<<<BATCH + PE_BLOCKS, TPB_PREP, 0, stream>>>(tok, seg, pe);
        out_kernel<<<OUT_BLOCKS, 256, 0, stream>>>(tok, seg, emb, pe, out);
        // DIAGNOSTIC: second identical launch. Idempotent (same bytes
        // rewritten). Marginal time vs R8 == true out_kernel duration.
        out_kernel<<<OUT_BLOCKS, 256, 0, stream>>>(tok, seg, emb, pe, out);
    } else {
        prep_kernel<<<BATCH, TPB_PREP, 0, stream>>>(tok, seg, pe);
        out_kernel_trig<<<OUT_BLOCKS, 256, 0, stream>>>(tok, seg, emb, out);
    }
}

// Round 13
// 35.956 us; speedup vs baseline: 4.7423x; 1.7277x over previous
//
#include <hip/hip_runtime.h>
#include <hip/hip_bf16.h>

#define BATCH 8
#define SEQ   8192
#define DIM   512

typedef float f32x4 __attribute__((ext_vector_type(4)));

#define INV2PI   0.15915494309189535f
#define SQRT_DIM 22.62741699796952f
// -log2(10000)/256  (div[k] = 2^(C2*k) = exp(-2k*ln(10000)/512))
#define C2 (-0.05190512648261504f)

// Workspace: [0,256KB) seg ids (int32). No pe table anymore.
#define SEG_BYTES ((size_t)BATCH * SEQ * 4)

#define TPB_PREP  1024
#define SEG_CHUNK (SEQ / TPB_PREP)          // 8 tokens / thread
#define NWAVE     (TPB_PREP / 64)           // 16

// LDS index, +1 int per 8: addr = 9t+j -> 2-way bank alias only (free)
#define TIX(k) ((k) + ((k) >> 3))

// ---------------------------------------------------------------------------
// seg_kernel: R8's proven scan, seg-only (pe fill deleted).
// One block (1024 thr) per batch row.
//
// seg reference (step i = 1..SEQ-1, carry nc starts 0):
//   c=t[i]; p=t[i-1];
//   if (36<=c<=41) nc=2;
//   is_note = c<12;
//   flag = is_note ? ((p>=12)||(nc>0)) : (p<12);
//   if (is_note) nc-=1;
//   seg = inclusive cumsum of flags (flag for token 0 = 0)
//
// nc chunk transform (reset,val): T(nc)=reset?val:nc+val; applied to nc=0 the
// prefix value is just val. compose(earlier A, later B) =
//   B.reset ? B : {A.reset, A.val+B.val}.
// ---------------------------------------------------------------------------
__global__ __launch_bounds__(TPB_PREP)
void seg_kernel(const int* __restrict__ tok, int* __restrict__ seg) {
    __shared__ int s_tok[SEQ + SEQ / 8];   // 36 KB
    __shared__ int s_seg[SEQ + SEQ / 8];   // 36 KB
    __shared__ int s_pr[NWAVE], s_pv[NWAVE], s_cnt[NWAVE];

    const int tid  = threadIdx.x;
    const int lane = tid & 63;
    const int wv   = tid >> 6;

    const int b  = blockIdx.x;
    const int* t = tok + (size_t)b * SEQ;
    int*      sg = seg + (size_t)b * SEQ;

    #pragma unroll
    for (int m = 0; m < SEG_CHUNK; ++m) {
        const int k = m * TPB_PREP + tid;
        s_tok[TIX(k)] = t[k];
    }
    __syncthreads();

    const int start = tid * SEG_CHUNK;
    const int end   = start + SEG_CHUNK;
    const int lo    = (start < 1) ? 1 : start;

    // ---- pass 1: per-thread nc transform --------------------------------
    int reset = 0, val = 0;
    #pragma unroll
    for (int i = lo; i < end; ++i) {
        const int c = s_tok[TIX(i)];
        if (c >= 36 && c <= 41) { reset = 1; val = 2; }
        if (c < 12) val -= 1;
    }

    int ir = reset, iv = val;
    #pragma unroll
    for (int off = 1; off < 64; off <<= 1) {
        const int pv = __shfl_up(iv, off);
        const int pr = __shfl_up(ir, off);
        if (lane >= off && !ir) { iv += pv; ir = pr; }
    }
    int er = __shfl_up(ir, 1), ev = __shfl_up(iv, 1);
    if (lane == 0) { er = 0; ev = 0; }
    if (lane == 63) { s_pr[wv] = ir; s_pv[wv] = iv; }
    __syncthreads();
    int bv = 0;
    for (int w = 0; w < wv; ++w) {
        if (s_pr[w]) bv = s_pv[w]; else bv += s_pv[w];
    }
    const int nc_entry = er ? ev : (bv + ev);

    // ---- pass 2: per-thread flag count ----------------------------------
    int nc = nc_entry, total = 0;
    #pragma unroll
    for (int i = lo; i < end; ++i) {
        const int c = s_tok[TIX(i)];
        const int p = s_tok[TIX(i - 1)];
        if (c >= 36 && c <= 41) nc = 2;
        const bool is_note = (c < 12);
        const int f = is_note ? (int)((p >= 12) || (nc > 0)) : (int)(p < 12);
        if (is_note) nc -= 1;
        total += f;
    }

    int it = total;
    #pragma unroll
    for (int off = 1; off < 64; off <<= 1) {
        const int pv = __shfl_up(it, off);
        if (lane >= off) it += pv;
    }
    int et = __shfl_up(it, 1);
    if (lane == 0) et = 0;
    if (lane == 63) s_cnt[wv] = it;
    __syncthreads();
    int boff = 0;
    for (int w = 0; w < wv; ++w) boff += s_cnt[w];
    int run = boff + et;

    // ---- pass 3: recompute flags, cumsum into LDS, flush coalesced ------
    nc = nc_entry;
    if (start == 0) s_seg[TIX(0)] = 0;
    #pragma unroll
    for (int i = lo; i < end; ++i) {
        const int c = s_tok[TIX(i)];
        const int p = s_tok[TIX(i - 1)];
        if (c >= 36 && c <= 41) nc = 2;
        const bool is_note = (c < 12);
        const int f = is_note ? (int)((p >= 12) || (nc > 0)) : (int)(p < 12);
        if (is_note) nc -= 1;
        run += f;
        s_seg[TIX(i)] = run;
    }
    __syncthreads();
    #pragma unroll
    for (int m = 0; m < SEG_CHUNK; ++m) {
        const int k = m * TPB_PREP + tid;
        sg[k] = s_seg[TIX(k)];
    }
}

// ---------------------------------------------------------------------------
// out_kernel: out[row,d] = emb[tok[row],d]*sqrt(512) + pe(seg[row],d)
// computed INLINE (no pe table): pe(pos,2k)=sin(pos*div[k]),
// pe(pos,2k+1)=cos(pos*div[k]), div[k]=2^(C2*k).
//
// Exact R8 memory structure (proven 22.8us L2-warm):
//  - 16384 blocks x 256 thr, 1 wave = 1 row (max TLP — R10/R11 proved
//    looping waves regress).
//  - XCD slab swizzle: vb=(bid&7)*2048+bid>>3 -> each XCD owns one batch.
//  - dA/dB dense lane layout -> every load/store instr is a dense burst.
//  - wave-uniform row -> tok/seg scalar loads.
//  - NT stores (write-once output).
// Trig cost: 12 trans-ops/wave x 64K waves ~ 1.3us chip-wide, hidden under
// 23us of stores. Eliminates pe fill + 8MB write + 134MB read of table
// traffic, and the 512-block prep tail.
// ---------------------------------------------------------------------------
#define OUT_BLOCKS ((BATCH * SEQ) / 4)   // 16384

__global__ __launch_bounds__(256)
void out_kernel(const int*   __restrict__ tok,
                const int*   __restrict__ seg,
                const float* __restrict__ emb,
                float*       __restrict__ out) {
    // bijective slab swizzle: 16384 = 8 * 2048; each XCD owns one batch
    const int bid = (int)blockIdx.x;
    const int vb  = ((bid & 7) << 11) | (bid >> 3);

    const int lane = (int)threadIdx.x & 63;
    const int row  = __builtin_amdgcn_readfirstlane(
                        vb * 4 + ((int)threadIdx.x >> 6));

    const int   token = tok[row];   // scalar load (uniform)
    const float segf  = (float)seg[row];

    const int dA = lane << 2;
    const int dB = dA + 256;

    const float* erow = emb + (size_t)token * DIM;
    const f32x4 eA = *reinterpret_cast<const f32x4*>(erow + dA);
    const f32x4 eB = *reinterpret_cast<const f32x4*>(erow + dB);

    float vA[4], vB[4];
    #pragma unroll
    for (int j = 0; j < 2; ++j) {
        const float kA = (float)((dA >> 1) + j);
        float rA = segf * __builtin_amdgcn_exp2f(C2 * kA) * INV2PI;
        rA -= floorf(rA);
        vA[2 * j]     = __builtin_amdgcn_sinf(rA);
        vA[2 * j + 1] = __builtin_amdgcn_cosf(rA);

        const float kB = (float)((dB >> 1) + j);
        float rB = segf * __builtin_amdgcn_exp2f(C2 * kB) * INV2PI;
        rB -= floorf(rB);
        vB[2 * j]     = __builtin_amdgcn_sinf(rB);
        vB[2 * j + 1] = __builtin_amdgcn_cosf(rB);
    }

    f32x4 oA, oB;
    oA.x = eA.x * SQRT_DIM + vA[0];  oA.y = eA.y * SQRT_DIM + vA[1];
    oA.z = eA.z * SQRT_DIM + vA[2];  oA.w = eA.w * SQRT_DIM + vA[3];
    oB.x = eB.x * SQRT_DIM + vB[0];  oB.y = eB.y * SQRT_DIM + vB[1];
    oB.z = eB.z * SQRT_DIM + vB[2];  oB.w = eB.w * SQRT_DIM + vB[3];

    float* orow = out + (size_t)row * DIM;
    __builtin_nontemporal_store(oA, reinterpret_cast<f32x4*>(orow + dA));
    __builtin_nontemporal_store(oB, reinterpret_cast<f32x4*>(orow + dB));
}

extern "C" void kernel_launch(void* const* d_in, const int* in_sizes, int n_in,
                              void* d_out, int out_size, void* d_ws, size_t ws_size,
                              hipStream_t stream) {
    const int*   tok = (const int*)d_in[0];     // (BATCH, SEQ) int32
    const float* emb = (const float*)d_in[1];   // (VOCAB, DIM) f32
    float*       out = (float*)d_out;           // (BATCH, SEQ, DIM) f32
    int*         seg = (int*)d_ws;              // 256 KB scratch

    seg_kernel<<<BATCH, TPB_PREP, 0, stream>>>(tok, seg);
    out_kernel<<<OUT_BLOCKS, 256, 0, stream>>>(tok, seg, emb, out);
}

// Round 14
// 34.281 us; speedup vs baseline: 4.9740x; 1.0489x over previous
//
#include <hip/hip_runtime.h>
#include <hip/hip_bf16.h>

#define BATCH 8
#define SEQ   8192
#define DIM   512

typedef float f32x4 __attribute__((ext_vector_type(4)));

#define INV2PI   0.15915494309189535f
#define SQRT_DIM 22.62741699796952f
// -log2(10000)/256  (div[k] = 2^(C2*k) = exp(-2k*ln(10000)/512))
#define C2 (-0.05190512648261504f)

// Workspace: [0,256KB) seg ids (int32).
#define SEG_BYTES ((size_t)BATCH * SEQ * 4)

// ---------------------------------------------------------------------------
// seg_kernel — REGISTER-RESIDENT rewrite (R13's was 72KB-LDS/3-pass/7-barrier
// and cost ~12us by subtraction; this is the single changed variable).
//
// One block per batch row, 256 threads, 32 tokens/thread in registers
// (8 x int4, fully unrolled -> static indexing, no scratch). Two barriers.
//
// Reference scan (step i = 1..SEQ-1, carry nc starts 0):
//   c=t[i]; p=t[i-1];
//   if (36<=c<=41) nc=2;
//   is_note = c<12;
//   flag = is_note ? ((p>=12)||(nc>0)) : (p<12);
//   if (is_note) nc-=1;
//   seg = inclusive cumsum of flags (flag for token 0 = 0)
//
// nc chunk transform (reset,val): T(nc)=reset?val:nc+val; applied to nc=0
// the prefix value is just val. compose(earlier A, later B) =
//   B.reset ? B : {A.reset, A.val+B.val}.
// ---------------------------------------------------------------------------
#define SEG_TPB 256
#define SCHUNK  (SEQ / SEG_TPB)   // 32

__global__ __launch_bounds__(SEG_TPB)
void seg_kernel(const int* __restrict__ tok, int* __restrict__ seg) {
    __shared__ int s_r[4], s_v[4], s_c[4];

    const int tid  = (int)threadIdx.x;
    const int lane = tid & 63;
    const int wv   = tid >> 6;
    const int b    = (int)blockIdx.x;
    const int* t   = tok + (size_t)b * SEQ;
    int*      sg   = seg + (size_t)b * SEQ;

    const int start = tid * SCHUNK;

    // ---- stage 32 tokens into registers (8 x int4) ----------------------
    int4 tt[8];
    #pragma unroll
    for (int m = 0; m < 8; ++m)
        tt[m] = *reinterpret_cast<const int4*>(t + start + m * 4);

    // entry "prev" token (t[start-1]); L2-hit (lines already being fetched)
    const int pentry = (start > 0) ? t[start - 1] : 0;

    int c[SCHUNK];
    #pragma unroll
    for (int m = 0; m < 8; ++m) {
        c[4 * m + 0] = tt[m].x;  c[4 * m + 1] = tt[m].y;
        c[4 * m + 2] = tt[m].z;  c[4 * m + 3] = tt[m].w;
    }

    // ---- pass 1: per-thread nc transform (reset,val), regs only ---------
    int reset = 0, val = 0;
    #pragma unroll
    for (int i = 0; i < SCHUNK; ++i) {
        if (i == 0 && start == 0) continue;     // token 0 never "current"
        const int cc = c[i];
        if (cc >= 36 && cc <= 41) { reset = 1; val = 2; }
        if (cc < 12) val -= 1;
    }

    // wave-inclusive monoid scan (6 shfl)
    int ir = reset, iv = val;
    #pragma unroll
    for (int off = 1; off < 64; off <<= 1) {
        const int pv = __shfl_up(iv, off);
        const int pr = __shfl_up(ir, off);
        if (lane >= off && !ir) { iv += pv; ir = pr; }
    }
    int er = __shfl_up(ir, 1), ev = __shfl_up(iv, 1);
    if (lane == 0) { er = 0; ev = 0; }
    if (lane == 63) { s_r[wv] = ir; s_v[wv] = iv; }
    __syncthreads();
    int bv = 0;
    #pragma unroll
    for (int w = 0; w < 4; ++w) {
        if (w < wv) { if (s_r[w]) bv = s_v[w]; else bv += s_v[w]; }
    }
    const int nc_entry = er ? ev : (bv + ev);

    // ---- pass 2+3 fused: flags + local prefix in regs -------------------
    int nc = nc_entry, cum = 0;
    int pref[SCHUNK];
    int p = pentry;
    #pragma unroll
    for (int i = 0; i < SCHUNK; ++i) {
        const int cc = c[i];
        int f = 0;
        if (!(i == 0 && start == 0)) {
            if (cc >= 36 && cc <= 41) nc = 2;
            const bool is_note = (cc < 12);
            f = is_note ? (int)((p >= 12) || (nc > 0)) : (int)(p < 12);
            if (is_note) nc -= 1;
        }
        cum += f;
        pref[i] = cum;
        p = cc;
    }

    // wave add-scan of totals
    int it = cum;
    #pragma unroll
    for (int off = 1; off < 64; off <<= 1) {
        const int pv = __shfl_up(it, off);
        if (lane >= off) it += pv;
    }
    int et = __shfl_up(it, 1);
    if (lane == 0) et = 0;
    if (lane == 63) s_c[wv] = it;
    __syncthreads();
    int boff = 0;
    #pragma unroll
    for (int w = 0; w < 4; ++w) {
        if (w < wv) boff += s_c[w];
    }
    const int run = boff + et;

    // ---- store: seg[start+i] = run + pref[i], as int4 -------------------
    #pragma unroll
    for (int m = 0; m < 8; ++m) {
        int4 o;
        o.x = run + pref[4 * m + 0];
        o.y = run + pref[4 * m + 1];
        o.z = run + pref[4 * m + 2];
        o.w = run + pref[4 * m + 3];
        *reinterpret_cast<int4*>(sg + start + m * 4) = o;
    }
}

// ---------------------------------------------------------------------------
// out_kernel: BYTE-IDENTICAL to R13 (proven 36.0us total; single-variable
// discipline). out[row,d] = emb[tok[row],d]*sqrt(512) + pe(seg[row],d),
// pe computed inline; R8 memory structure (dense dA/dB bursts, XCD slab
// swizzle, wave-uniform scalar tok/seg, NT stores).
// ---------------------------------------------------------------------------
#define OUT_BLOCKS ((BATCH * SEQ) / 4)   // 16384

__global__ __launch_bounds__(256)
void out_kernel(const int*   __restrict__ tok,
                const int*   __restrict__ seg,
                const float* __restrict__ emb,
                float*       __restrict__ out) {
    // bijective slab swizzle: 16384 = 8 * 2048; each XCD owns one batch
    const int bid = (int)blockIdx.x;
    const int vb  = ((bid & 7) << 11) | (bid >> 3);

    const int lane = (int)threadIdx.x & 63;
    const int row  = __builtin_amdgcn_readfirstlane(
                        vb * 4 + ((int)threadIdx.x >> 6));

    const int   token = tok[row];   // scalar load (uniform)
    const float segf  = (float)seg[row];

    const int dA = lane << 2;
    const int dB = dA + 256;

    const float* erow = emb + (size_t)token * DIM;
    const f32x4 eA = *reinterpret_cast<const f32x4*>(erow + dA);
    const f32x4 eB = *reinterpret_cast<const f32x4*>(erow + dB);

    float vA[4], vB[4];
    #pragma unroll
    for (int j = 0; j < 2; ++j) {
        const float kA = (float)((dA >> 1) + j);
        float rA = segf * __builtin_amdgcn_exp2f(C2 * kA) * INV2PI;
        rA -= floorf(rA);
        vA[2 * j]     = __builtin_amdgcn_sinf(rA);
        vA[2 * j + 1] = __builtin_amdgcn_cosf(rA);

        const float kB = (float)((dB >> 1) + j);
        float rB = segf * __builtin_amdgcn_exp2f(C2 * kB) * INV2PI;
        rB -= floorf(rB);
        vB[2 * j]     = __builtin_amdgcn_sinf(rB);
        vB[2 * j + 1] = __builtin_amdgcn_cosf(rB);
    }

    f32x4 oA, oB;
    oA.x = eA.x * SQRT_DIM + vA[0];  oA.y = eA.y * SQRT_DIM + vA[1];
    oA.z = eA.z * SQRT_DIM + vA[2];  oA.w = eA.w * SQRT_DIM + vA[3];
    oB.x = eB.x * SQRT_DIM + vB[0];  oB.y = eB.y * SQRT_DIM + vB[1];
    oB.z = eB.z * SQRT_DIM + vB[2];  oB.w = eB.w * SQRT_DIM + vB[3];

    float* orow = out + (size_t)row * DIM;
    __builtin_nontemporal_store(oA, reinterpret_cast<f32x4*>(orow + dA));
    __builtin_nontemporal_store(oB, reinterpret_cast<f32x4*>(orow + dB));
}

extern "C" void kernel_launch(void* const* d_in, const int* in_sizes, int n_in,
                              void* d_out, int out_size, void* d_ws, size_t ws_size,
                              hipStream_t stream) {
    const int*   tok = (const int*)d_in[0];     // (BATCH, SEQ) int32
    const float* emb = (const float*)d_in[1];   // (VOCAB, DIM) f32
    float*       out = (float*)d_out;           // (BATCH, SEQ, DIM) f32
    int*         seg = (int*)d_ws;              // 256 KB scratch

    seg_kernel<<<BATCH, SEG_TPB, 0, stream>>>(tok, seg);
    out_kernel<<<OUT_BLOCKS, 256, 0, stream>>>(tok, seg, emb, out);
}